// Round 4
// baseline (353.013 us; speedup 1.0000x reference)
//
#include <hip/hip_runtime.h>

#define NEG (-1e30f)

constexpr int Bn = 16;
constexpr int Tn = 512;
constexpr int Dn = 256;
constexpr int Vn = 4233;
constexpr int Vp = 4288;   // V padded to 67*64
constexpr int Ln = 64;     // LMAX
constexpr int Un = 80;     // padded gathered-label count (65 -> 80 = 5*16)
constexpr int LP = 72;     // LDS row stride in bf16 (64 + 8 pad)
constexpr int CS = 68;     // ctc LDS row stride in floats
constexpr int NCB = 67;    // number of column blocks in gemm_se
constexpr int Mtot = Bn * Tn;  // 8192

typedef __attribute__((ext_vector_type(8))) short short8;
typedef __attribute__((ext_vector_type(4))) float f32x4;

__device__ __forceinline__ float lae2(float x, float y) {
    float m = fmaxf(x, y);
    return m + __logf(__expf(x - m) + __expf(y - m));
}
__device__ __forceinline__ float lae3(float x, float y, float z) {
    float m = fmaxf(fmaxf(x, y), z);
    return m + __logf(__expf(x - m) + __expf(y - m) + __expf(z - m));
}

__device__ __forceinline__ unsigned short cvt_bf16(float f) {
    unsigned int u = __float_as_uint(f);
    u = (u + 0x7fffu + ((u >> 16) & 1u)) >> 16;
    return (unsigned short)u;
}

// ---------------- conversion / gather prep ----------------
__global__ __launch_bounds__(256) void conv(
    const float* __restrict__ hs, const float* __restrict__ W,
    const float* __restrict__ bias, const int* __restrict__ ys,
    unsigned short* __restrict__ hs_b, unsigned short* __restrict__ w_b,
    unsigned short* __restrict__ wg_b, float* __restrict__ gbias)
{
    const int gid = blockIdx.x * 256 + threadIdx.x;
    const int stride = gridDim.x * 256;
    const float4* hs4 = (const float4*)hs;
    const float4* W4  = (const float4*)W;

    for (int i = gid; i < (Bn * Tn * Dn) / 4; i += stride) {
        float4 v = hs4[i];
        ushort4 o = make_ushort4(cvt_bf16(v.x), cvt_bf16(v.y), cvt_bf16(v.z), cvt_bf16(v.w));
        *(ushort4*)(&hs_b[i * 4]) = o;
    }
    for (int i = gid; i < Vp * (Dn / 4); i += stride) {
        int row = i >> 6;
        float4 v = make_float4(0.f, 0.f, 0.f, 0.f);
        if (row < Vn) v = W4[i];
        ushort4 o = make_ushort4(cvt_bf16(v.x), cvt_bf16(v.y), cvt_bf16(v.z), cvt_bf16(v.w));
        *(ushort4*)(&w_b[i * 4]) = o;
    }
    for (int i = gid; i < Bn * Un * (Dn / 4); i += stride) {
        int b = i / (Un * (Dn / 4));
        int rem = i - b * (Un * (Dn / 4));
        int u = rem >> 6;
        int k4 = rem & 63;
        int v = (u == 0) ? 0 : ((u <= Ln) ? ys[b * Ln + u - 1] : -1);
        float4 val = make_float4(0.f, 0.f, 0.f, 0.f);
        if (v >= 0) val = W4[(size_t)v * (Dn / 4) + k4];
        ushort4 o = make_ushort4(cvt_bf16(val.x), cvt_bf16(val.y), cvt_bf16(val.z), cvt_bf16(val.w));
        *(ushort4*)(&wg_b[i * 4]) = o;
    }
    for (int i = gid; i < Bn * Un; i += stride) {
        int b = i / Un;
        int u = i - b * Un;
        int v = (u == 0) ? 0 : ((u <= Ln) ? ys[b * Ln + u - 1] : -1);
        gbias[i] = (v >= 0) ? bias[v] : 0.0f;
    }
}

// ---------------- main GEMM: partial sums of exp over V ----------------
// block tile 128 rows x 64 vocab; writes partial sum to sep[colblk][row].
__global__ __launch_bounds__(256) void gemm_se(
    const unsigned short* __restrict__ hs_b, const unsigned short* __restrict__ w_b,
    const float* __restrict__ bias, float* __restrict__ sep)
{
    __shared__ short lsA[128 * LP];
    __shared__ short lsB[64 * LP];

    const int tid = threadIdx.x;
    const int lane = tid & 63;
    const int w = tid >> 6;
    const int lr = lane & 15;
    const int kq = lane >> 4;
    const int m0 = blockIdx.x * 128;
    const int n0 = blockIdx.y * 64;
    const int mw = w * 32;

    f32x4 acc[2][4];
    #pragma unroll
    for (int mf = 0; mf < 2; ++mf)
        #pragma unroll
        for (int nf = 0; nf < 4; ++nf)
            acc[mf][nf] = (f32x4){0.f, 0.f, 0.f, 0.f};

    for (int ks = 0; ks < 4; ++ks) {
        const int k0 = ks * 64;
        float4 ga[4], gb2[2];
        #pragma unroll
        for (int j = 0; j < 4; ++j) {
            int ch = tid + 256 * j;
            int row = ch >> 3, off = (ch & 7) * 8;
            ga[j] = *(const float4*)(hs_b + (size_t)(m0 + row) * Dn + k0 + off);
        }
        #pragma unroll
        for (int j = 0; j < 2; ++j) {
            int ch = tid + 256 * j;
            int row = ch >> 3, off = (ch & 7) * 8;
            gb2[j] = *(const float4*)(w_b + (size_t)(n0 + row) * Dn + k0 + off);
        }
        __syncthreads();
        #pragma unroll
        for (int j = 0; j < 4; ++j) {
            int ch = tid + 256 * j;
            int row = ch >> 3, off = (ch & 7) * 8;
            *(float4*)(&lsA[row * LP + off]) = ga[j];
        }
        #pragma unroll
        for (int j = 0; j < 2; ++j) {
            int ch = tid + 256 * j;
            int row = ch >> 3, off = (ch & 7) * 8;
            *(float4*)(&lsB[row * LP + off]) = gb2[j];
        }
        __syncthreads();

        #pragma unroll
        for (int sub = 0; sub < 2; ++sub) {
            short8 af[2], bf[4];
            #pragma unroll
            for (int mf = 0; mf < 2; ++mf)
                af[mf] = *(const short8*)(&lsA[(mw + mf * 16 + lr) * LP + sub * 32 + kq * 8]);
            #pragma unroll
            for (int nf = 0; nf < 4; ++nf)
                bf[nf] = *(const short8*)(&lsB[(nf * 16 + lr) * LP + sub * 32 + kq * 8]);
            #pragma unroll
            for (int mf = 0; mf < 2; ++mf)
                #pragma unroll
                for (int nf = 0; nf < 4; ++nf)
                    acc[mf][nf] = __builtin_amdgcn_mfma_f32_16x16x32_bf16(
                        af[mf], bf[nf], acc[mf][nf], 0, 0, 0);
        }
    }

    float bcol[4]; bool valid[4];
    #pragma unroll
    for (int nf = 0; nf < 4; ++nf) {
        int col = n0 + nf * 16 + lr;
        valid[nf] = (col < Vn);
        bcol[nf] = valid[nf] ? bias[col] : 0.0f;
    }
    #pragma unroll
    for (int mf = 0; mf < 2; ++mf) {
        #pragma unroll
        for (int r = 0; r < 4; ++r) {
            float s = 0.0f;
            #pragma unroll
            for (int nf = 0; nf < 4; ++nf)
                if (valid[nf]) s += __expf(acc[mf][nf][r] + bcol[nf]);
            #pragma unroll
            for (int off = 1; off < 16; off <<= 1) s += __shfl_xor(s, off, 64);
            if (lr == 0)
                sep[(size_t)blockIdx.y * Mtot + m0 + mw + mf * 16 + kq * 4 + r] = s;
        }
    }
}

// ---------------- gathered-label GEMM -> normalized log-probs ----------------
// Fuses the cross-column-block reduction of sep (this block owns 128 distinct
// rows) and writes glp[b][t][u] = logit + bias - lse.
__global__ __launch_bounds__(256) void gemm_gather(
    const unsigned short* __restrict__ hs_b, const unsigned short* __restrict__ wg_b,
    const float* __restrict__ gbias, const float* __restrict__ sep,
    float* __restrict__ glp)
{
    __shared__ short lsA[128 * LP];
    __shared__ short lsB[Un * LP];
    __shared__ float red2[128][2];
    __shared__ float sh_lse[128];

    const int tid = threadIdx.x;
    const int lane = tid & 63;
    const int w = tid >> 6;
    const int lr = lane & 15;
    const int kq = lane >> 4;
    const int m0 = blockIdx.x * 128;
    const int b = blockIdx.y;
    const int mw = w * 32;

    f32x4 acc[2][5];
    #pragma unroll
    for (int mf = 0; mf < 2; ++mf)
        #pragma unroll
        for (int nf = 0; nf < 5; ++nf)
            acc[mf][nf] = (f32x4){0.f, 0.f, 0.f, 0.f};

    for (int ks = 0; ks < 4; ++ks) {
        const int k0 = ks * 64;
        float4 ga[4];
        #pragma unroll
        for (int j = 0; j < 4; ++j) {
            int ch = tid + 256 * j;
            int row = ch >> 3, off = (ch & 7) * 8;
            ga[j] = *(const float4*)(hs_b + (size_t)(b * Tn + m0 + row) * Dn + k0 + off);
        }
        float4 gbv[3];
        int nb = 0;
        for (int ch = tid; ch < Un * 8; ch += 256, ++nb) {
            int row = ch >> 3, off = (ch & 7) * 8;
            gbv[nb] = *(const float4*)(wg_b + (size_t)(b * Un + row) * Dn + k0 + off);
        }
        __syncthreads();
        #pragma unroll
        for (int j = 0; j < 4; ++j) {
            int ch = tid + 256 * j;
            int row = ch >> 3, off = (ch & 7) * 8;
            *(float4*)(&lsA[row * LP + off]) = ga[j];
        }
        nb = 0;
        for (int ch = tid; ch < Un * 8; ch += 256, ++nb) {
            int row = ch >> 3, off = (ch & 7) * 8;
            *(float4*)(&lsB[row * LP + off]) = gbv[nb];
        }
        __syncthreads();

        #pragma unroll
        for (int sub = 0; sub < 2; ++sub) {
            short8 af[2], bf[5];
            #pragma unroll
            for (int mf = 0; mf < 2; ++mf)
                af[mf] = *(const short8*)(&lsA[(mw + mf * 16 + lr) * LP + sub * 32 + kq * 8]);
            #pragma unroll
            for (int nf = 0; nf < 5; ++nf)
                bf[nf] = *(const short8*)(&lsB[(nf * 16 + lr) * LP + sub * 32 + kq * 8]);
            #pragma unroll
            for (int mf = 0; mf < 2; ++mf)
                #pragma unroll
                for (int nf = 0; nf < 5; ++nf)
                    acc[mf][nf] = __builtin_amdgcn_mfma_f32_16x16x32_bf16(
                        af[mf], bf[nf], acc[mf][nf], 0, 0, 0);
        }
    }

    // fused lse reduction: sum sep[c][b*Tn + m0 + r] over c in [0,67)
    {
        int r = tid >> 1, half = tid & 1;
        int g = b * Tn + m0 + r;
        float s = 0.0f;
        #pragma unroll 2
        for (int j = 0; j < 34; ++j) {
            int c = half * 34 + j;
            if (c < NCB) s += sep[(size_t)c * Mtot + g];
        }
        red2[r][half] = s;
    }
    __syncthreads();
    if (tid < 128) sh_lse[tid] = __logf(red2[tid][0] + red2[tid][1]);
    __syncthreads();

    #pragma unroll
    for (int mf = 0; mf < 2; ++mf) {
        #pragma unroll
        for (int r = 0; r < 4; ++r) {
            int lrow = mw + mf * 16 + kq * 4 + r;
            int t = m0 + lrow;
            float lse = sh_lse[lrow];
            #pragma unroll
            for (int nf = 0; nf < 5; ++nf) {
                int u = nf * 16 + lr;
                glp[((size_t)(b * Tn + t)) * Un + u] =
                    acc[mf][nf][r] + gbias[b * Un + u] - lse;
            }
        }
    }
}

// ---------------- CTC forward recursion ----------------
__global__ __launch_bounds__(256) void ctc_fwd(
    const float* __restrict__ glp, const int* __restrict__ ys,
    const int* __restrict__ hlens, const int* __restrict__ ylens,
    float* __restrict__ ll_out)
{
    __shared__ float ls[2][64 * CS + 4];
    __shared__ float sh[132];

    const int b = blockIdx.x;
    const int tid = threadIdx.x;
    const int l = tid & 63;

    int yl = ys[b * Ln + l];
    int ylm = (l >= 1) ? ys[b * Ln + l - 1] : -1;
    const bool allow1 = (l >= 1) && (yl != ylm);
    const int hl = hlens[b];

    const float* gb = glp + (size_t)b * Tn * Un;

    {
        const float* src = gb;
        #pragma unroll
        for (int j = 0; j < 4; ++j) {
            int i = tid + j * 256;
            int tt = i >> 4, u4 = (i & 15) * 4;
            *(float4*)(&ls[0][tt * CS + u4]) = *(const float4*)(src + tt * 80 + u4);
        }
        if (tid < 64) ls[0][tid * CS + 64] = src[tid * 80 + 64];
    }
    __syncthreads();

    float a0 = (l == 0) ? ls[0][0] : NEG;
    float a1 = (l == 0) ? ls[0][1] : NEG;
    float a2 = NEG;

    float4 r4[4];
    float r1 = 0.0f;

    for (int c = 0; c < 8; ++c) {
        if (c < 7) {
            const float* src = gb + (size_t)(c + 1) * 64 * 80;
            #pragma unroll
            for (int j = 0; j < 4; ++j) {
                int i = tid + j * 256;
                int tt = i >> 4, u4 = (i & 15) * 4;
                r4[j] = *(const float4*)(src + tt * 80 + u4);
            }
            if (tid < 64) r1 = src[tid * 80 + 64];
        }

        const float* buf = ls[c & 1];
        const int tstart = (c == 0) ? 1 : 0;
        const int tbase = c * 64;
        for (int tt = tstart; tt < 64; ++tt) {
            float lpb = buf[tt * CS];
            float lpl = buf[tt * CS + 1 + l];

            float p1 = __shfl_up(a1, 1, 64);
            if (l == 0) p1 = NEG;

            float u0 = lae2(a0, p1) + lpb;
            float u1 = lae3(a1, a0, allow1 ? p1 : NEG) + lpl;
            float u2 = lae2(a2, a1) + lpb;

            bool act = (tbase + tt) < hl;
            a0 = act ? u0 : a0;
            a1 = act ? u1 : a1;
            a2 = act ? u2 : a2;
        }

        if (c < 7) {
            float* dst = ls[(c + 1) & 1];
            #pragma unroll
            for (int j = 0; j < 4; ++j) {
                int i = tid + j * 256;
                int tt = i >> 4, u4 = (i & 15) * 4;
                *(float4*)(&dst[tt * CS + u4]) = r4[j];
            }
            if (tid < 64) dst[tid * CS + 64] = r1;
        }
        __syncthreads();
    }

    if (tid < 64) {
        sh[2 * l] = a0;
        sh[2 * l + 1] = a1;
        if (l == 63) sh[128] = a2;
    }
    __syncthreads();

    if (tid == 0) {
        int L = ylens[b];
        ll_out[b] = lae2(sh[2 * L], sh[2 * L - 1]);
    }
}

__global__ void finalize(const float* __restrict__ ll, float* __restrict__ out) {
    if (threadIdx.x == 0 && blockIdx.x == 0) {
        float s = 0.0f;
        #pragma unroll
        for (int b = 0; b < Bn; ++b) s += ll[b];
        out[0] = -s / (float)Bn;
    }
}

extern "C" void kernel_launch(void* const* d_in, const int* in_sizes, int n_in,
                              void* d_out, int out_size, void* d_ws, size_t ws_size,
                              hipStream_t stream) {
    const float* hs    = (const float*)d_in[0];
    const int*   hlens = (const int*)d_in[1];
    const int*   ys    = (const int*)d_in[2];
    const int*   ylens = (const int*)d_in[3];
    const float* W     = (const float*)d_in[4];
    const float* bias  = (const float*)d_in[5];
    float* out = (float*)d_out;

    char* ws = (char*)d_ws;
    unsigned short* hs_b = (unsigned short*)(ws);                       // 4,194,304 B
    unsigned short* w_b  = (unsigned short*)(ws + 4194304);             // 2,195,456 B
    unsigned short* wg_b = (unsigned short*)(ws + 6389760);             //   655,360 B
    float* glp   = (float*)(ws + 7045120);                              // 2,621,440 B
    float* sep   = (float*)(ws + 9666560);                              // 2,195,456 B
    float* gbias = (float*)(ws + 11862016);                             //     5,120 B
    float* ll    = (float*)(ws + 11867136);                             //        64 B

    conv<<<1024, 256, 0, stream>>>(hs, W, bias, ys, hs_b, w_b, wg_b, gbias);
    gemm_se<<<dim3(64, NCB), 256, 0, stream>>>(hs_b, w_b, bias, sep);
    gemm_gather<<<dim3(4, 16), 256, 0, stream>>>(hs_b, wg_b, gbias, sep, glp);
    ctc_fwd<<<Bn, 256, 0, stream>>>(glp, ys, hlens, ylens, ll);
    finalize<<<1, 64, 0, stream>>>(ll, out);
}

// Round 5
// 244.552 us; speedup vs baseline: 1.4435x; 1.4435x over previous
//
#include <hip/hip_runtime.h>

#define NEG (-1e30f)

constexpr int Bn = 16;
constexpr int Tn = 512;
constexpr int Dn = 256;
constexpr int Vn = 4233;
constexpr int Vp = 4352;   // V padded to 34*128
constexpr int Ln = 64;     // LMAX
constexpr int Un = 80;     // padded gathered-label count (65 -> 80 = 5*16)
constexpr int LP = 72;     // LDS row stride in bf16 for gemm_gather (64 + 8 pad)
constexpr int CS = 68;     // ctc LDS row stride in floats
constexpr int NCB = 34;    // number of 128-wide column blocks in gemm_se
constexpr int Mtot = Bn * Tn;  // 8192

typedef __attribute__((ext_vector_type(8))) short short8;
typedef __attribute__((ext_vector_type(4))) float f32x4;

__device__ __forceinline__ float lae2(float x, float y) {
    float m = fmaxf(x, y);
    return m + __logf(__expf(x - m) + __expf(y - m));
}
__device__ __forceinline__ float lae3(float x, float y, float z) {
    float m = fmaxf(fmaxf(x, y), z);
    return m + __logf(__expf(x - m) + __expf(y - m) + __expf(z - m));
}

__device__ __forceinline__ unsigned short cvt_bf16(float f) {
    unsigned int u = __float_as_uint(f);
    u = (u + 0x7fffu + ((u >> 16) & 1u)) >> 16;
    return (unsigned short)u;
}

// async global->LDS, 16B per lane; LDS dest is wave-uniform base + lane*16
__device__ __forceinline__ void gl_lds16(const void* g, void* l) {
    __builtin_amdgcn_global_load_lds(
        (const __attribute__((address_space(1))) void*)g,
        (__attribute__((address_space(3))) void*)l,
        16, 0, 0);
}

// ---------------- conversion / gather prep ----------------
__global__ __launch_bounds__(256) void conv(
    const float* __restrict__ hs, const float* __restrict__ W,
    const float* __restrict__ bias, const int* __restrict__ ys,
    unsigned short* __restrict__ hs_b, unsigned short* __restrict__ w_b,
    unsigned short* __restrict__ wg_b, float* __restrict__ gbias)
{
    const int gid = blockIdx.x * 256 + threadIdx.x;
    const int stride = gridDim.x * 256;
    const float4* hs4 = (const float4*)hs;
    const float4* W4  = (const float4*)W;

    for (int i = gid; i < (Bn * Tn * Dn) / 4; i += stride) {
        float4 v = hs4[i];
        ushort4 o = make_ushort4(cvt_bf16(v.x), cvt_bf16(v.y), cvt_bf16(v.z), cvt_bf16(v.w));
        *(ushort4*)(&hs_b[i * 4]) = o;
    }
    for (int i = gid; i < Vp * (Dn / 4); i += stride) {
        int row = i >> 6;
        float4 v = make_float4(0.f, 0.f, 0.f, 0.f);
        if (row < Vn) v = W4[i];
        ushort4 o = make_ushort4(cvt_bf16(v.x), cvt_bf16(v.y), cvt_bf16(v.z), cvt_bf16(v.w));
        *(ushort4*)(&w_b[i * 4]) = o;
    }
    for (int i = gid; i < Bn * Un * (Dn / 4); i += stride) {
        int b = i / (Un * (Dn / 4));
        int rem = i - b * (Un * (Dn / 4));
        int u = rem >> 6;
        int k4 = rem & 63;
        int v = (u == 0) ? 0 : ((u <= Ln) ? ys[b * Ln + u - 1] : -1);
        float4 val = make_float4(0.f, 0.f, 0.f, 0.f);
        if (v >= 0) val = W4[(size_t)v * (Dn / 4) + k4];
        ushort4 o = make_ushort4(cvt_bf16(val.x), cvt_bf16(val.y), cvt_bf16(val.z), cvt_bf16(val.w));
        *(ushort4*)(&wg_b[i * 4]) = o;
    }
    for (int i = gid; i < Bn * Un; i += stride) {
        int b = i / Un;
        int u = i - b * Un;
        int v = (u == 0) ? 0 : ((u <= Ln) ? ys[b * Ln + u - 1] : -1);
        gbias[i] = (v >= 0) ? bias[v] : 0.0f;
    }
}

// ---------------- main GEMM: partial sums of exp over V ----------------
// m97-style 128x128 tile, K staged 64/iter via global_load_lds (16B),
// unpadded LDS (row stride 64 bf16). 4 waves, each 32 rows x 128 cols.
// Writes partial sum of exp to sep[colblk][row].
__global__ __launch_bounds__(256) void gemm_se(
    const unsigned short* __restrict__ hs_b, const unsigned short* __restrict__ w_b,
    const float* __restrict__ bias, float* __restrict__ sep)
{
    __shared__ __align__(16) short lsA[128 * 64];
    __shared__ __align__(16) short lsB[128 * 64];

    const int tid = threadIdx.x;
    const int lane = tid & 63;
    const int w = tid >> 6;
    const int lr = lane & 15;
    const int kq = lane >> 4;
    const int m0 = blockIdx.x * 128;
    const int n0 = blockIdx.y * 128;
    const int mw = w * 32;

    const int srow = lane >> 3;        // sub-row within 8-row chunk
    const int scol = (lane & 7) * 8;   // bf16 offset within 64-col row (16B granules)

    f32x4 acc[2][8];
    #pragma unroll
    for (int mf = 0; mf < 2; ++mf)
        #pragma unroll
        for (int nf = 0; nf < 8; ++nf)
            acc[mf][nf] = (f32x4){0.f, 0.f, 0.f, 0.f};

    for (int ks = 0; ks < 4; ++ks) {
        const int k0 = ks * 64;
        __syncthreads();   // previous stage's LDS reads complete before overwrite
        #pragma unroll
        for (int j = 0; j < 4; ++j) {
            int c = w * 4 + j;                  // chunk 0..15, wave-uniform
            int row = c * 8 + srow;
            gl_lds16(hs_b + (size_t)(m0 + row) * Dn + k0 + scol, (char*)lsA + c * 1024);
            gl_lds16(w_b  + (size_t)(n0 + row) * Dn + k0 + scol, (char*)lsB + c * 1024);
        }
        __syncthreads();   // drains vmcnt(0) -> LDS populated

        #pragma unroll
        for (int sub = 0; sub < 2; ++sub) {
            short8 af[2], bf[8];
            #pragma unroll
            for (int mf = 0; mf < 2; ++mf)
                af[mf] = *(const short8*)(&lsA[(mw + mf * 16 + lr) * 64 + sub * 32 + kq * 8]);
            #pragma unroll
            for (int nf = 0; nf < 8; ++nf)
                bf[nf] = *(const short8*)(&lsB[(nf * 16 + lr) * 64 + sub * 32 + kq * 8]);
            #pragma unroll
            for (int mf = 0; mf < 2; ++mf)
                #pragma unroll
                for (int nf = 0; nf < 8; ++nf)
                    acc[mf][nf] = __builtin_amdgcn_mfma_f32_16x16x32_bf16(
                        af[mf], bf[nf], acc[mf][nf], 0, 0, 0);
        }
    }

    float bcol[8]; bool valid[8];
    #pragma unroll
    for (int nf = 0; nf < 8; ++nf) {
        int col = n0 + nf * 16 + lr;
        valid[nf] = (col < Vn);
        bcol[nf] = valid[nf] ? bias[col] : 0.0f;
    }
    #pragma unroll
    for (int mf = 0; mf < 2; ++mf) {
        #pragma unroll
        for (int r = 0; r < 4; ++r) {
            float s = 0.0f;
            #pragma unroll
            for (int nf = 0; nf < 8; ++nf)
                if (valid[nf]) s += __expf(acc[mf][nf][r] + bcol[nf]);
            #pragma unroll
            for (int off = 1; off < 16; off <<= 1) s += __shfl_xor(s, off, 64);
            if (lr == 0)
                sep[(size_t)blockIdx.y * Mtot + m0 + mw + mf * 16 + kq * 4 + r] = s;
        }
    }
}

// ---------------- gathered-label GEMM -> normalized log-probs ----------------
// Fuses the cross-column-block reduction of sep (this block owns 128 distinct
// rows) and writes glp[b][t][u] = logit + bias - lse.
__global__ __launch_bounds__(256) void gemm_gather(
    const unsigned short* __restrict__ hs_b, const unsigned short* __restrict__ wg_b,
    const float* __restrict__ gbias, const float* __restrict__ sep,
    float* __restrict__ glp)
{
    __shared__ short lsA[128 * LP];
    __shared__ short lsB[Un * LP];
    __shared__ float red2[128][2];
    __shared__ float sh_lse[128];

    const int tid = threadIdx.x;
    const int lane = tid & 63;
    const int w = tid >> 6;
    const int lr = lane & 15;
    const int kq = lane >> 4;
    const int m0 = blockIdx.x * 128;
    const int b = blockIdx.y;
    const int mw = w * 32;

    f32x4 acc[2][5];
    #pragma unroll
    for (int mf = 0; mf < 2; ++mf)
        #pragma unroll
        for (int nf = 0; nf < 5; ++nf)
            acc[mf][nf] = (f32x4){0.f, 0.f, 0.f, 0.f};

    for (int ks = 0; ks < 4; ++ks) {
        const int k0 = ks * 64;
        float4 ga[4];
        #pragma unroll
        for (int j = 0; j < 4; ++j) {
            int ch = tid + 256 * j;
            int row = ch >> 3, off = (ch & 7) * 8;
            ga[j] = *(const float4*)(hs_b + (size_t)(b * Tn + m0 + row) * Dn + k0 + off);
        }
        float4 gbv[3];
        int nb = 0;
        for (int ch = tid; ch < Un * 8; ch += 256, ++nb) {
            int row = ch >> 3, off = (ch & 7) * 8;
            gbv[nb] = *(const float4*)(wg_b + (size_t)(b * Un + row) * Dn + k0 + off);
        }
        __syncthreads();
        #pragma unroll
        for (int j = 0; j < 4; ++j) {
            int ch = tid + 256 * j;
            int row = ch >> 3, off = (ch & 7) * 8;
            *(float4*)(&lsA[row * LP + off]) = ga[j];
        }
        nb = 0;
        for (int ch = tid; ch < Un * 8; ch += 256, ++nb) {
            int row = ch >> 3, off = (ch & 7) * 8;
            *(float4*)(&lsB[row * LP + off]) = gbv[nb];
        }
        __syncthreads();

        #pragma unroll
        for (int sub = 0; sub < 2; ++sub) {
            short8 af[2], bf[5];
            #pragma unroll
            for (int mf = 0; mf < 2; ++mf)
                af[mf] = *(const short8*)(&lsA[(mw + mf * 16 + lr) * LP + sub * 32 + kq * 8]);
            #pragma unroll
            for (int nf = 0; nf < 5; ++nf)
                bf[nf] = *(const short8*)(&lsB[(nf * 16 + lr) * LP + sub * 32 + kq * 8]);
            #pragma unroll
            for (int mf = 0; mf < 2; ++mf)
                #pragma unroll
                for (int nf = 0; nf < 5; ++nf)
                    acc[mf][nf] = __builtin_amdgcn_mfma_f32_16x16x32_bf16(
                        af[mf], bf[nf], acc[mf][nf], 0, 0, 0);
        }
    }

    // fused lse reduction: sum sep[c][b*Tn + m0 + r] over c in [0,34)
    {
        int r = tid >> 1, half = tid & 1;
        int g = b * Tn + m0 + r;
        float s = 0.0f;
        #pragma unroll
        for (int j = 0; j < 17; ++j) {
            int c = half * 17 + j;
            s += sep[(size_t)c * Mtot + g];
        }
        red2[r][half] = s;
    }
    __syncthreads();
    if (tid < 128) sh_lse[tid] = __logf(red2[tid][0] + red2[tid][1]);
    __syncthreads();

    #pragma unroll
    for (int mf = 0; mf < 2; ++mf) {
        #pragma unroll
        for (int r = 0; r < 4; ++r) {
            int lrow = mw + mf * 16 + kq * 4 + r;
            int t = m0 + lrow;
            float lse = sh_lse[lrow];
            #pragma unroll
            for (int nf = 0; nf < 5; ++nf) {
                int u = nf * 16 + lr;
                glp[((size_t)(b * Tn + t)) * Un + u] =
                    acc[mf][nf][r] + gbias[b * Un + u] - lse;
            }
        }
    }
}

// ---------------- CTC forward recursion ----------------
__global__ __launch_bounds__(256) void ctc_fwd(
    const float* __restrict__ glp, const int* __restrict__ ys,
    const int* __restrict__ hlens, const int* __restrict__ ylens,
    float* __restrict__ ll_out)
{
    __shared__ float ls[2][64 * CS + 4];
    __shared__ float sh[132];

    const int b = blockIdx.x;
    const int tid = threadIdx.x;
    const int l = tid & 63;

    int yl = ys[b * Ln + l];
    int ylm = (l >= 1) ? ys[b * Ln + l - 1] : -1;
    const bool allow1 = (l >= 1) && (yl != ylm);
    const int hl = hlens[b];

    const float* gb = glp + (size_t)b * Tn * Un;

    {
        const float* src = gb;
        #pragma unroll
        for (int j = 0; j < 4; ++j) {
            int i = tid + j * 256;
            int tt = i >> 4, u4 = (i & 15) * 4;
            *(float4*)(&ls[0][tt * CS + u4]) = *(const float4*)(src + tt * 80 + u4);
        }
        if (tid < 64) ls[0][tid * CS + 64] = src[tid * 80 + 64];
    }
    __syncthreads();

    float a0 = (l == 0) ? ls[0][0] : NEG;
    float a1 = (l == 0) ? ls[0][1] : NEG;
    float a2 = NEG;

    float4 r4[4];
    float r1 = 0.0f;

    for (int c = 0; c < 8; ++c) {
        if (c < 7) {
            const float* src = gb + (size_t)(c + 1) * 64 * 80;
            #pragma unroll
            for (int j = 0; j < 4; ++j) {
                int i = tid + j * 256;
                int tt = i >> 4, u4 = (i & 15) * 4;
                r4[j] = *(const float4*)(src + tt * 80 + u4);
            }
            if (tid < 64) r1 = src[tid * 80 + 64];
        }

        const float* buf = ls[c & 1];
        const int tstart = (c == 0) ? 1 : 0;
        const int tbase = c * 64;
        for (int tt = tstart; tt < 64; ++tt) {
            float lpb = buf[tt * CS];
            float lpl = buf[tt * CS + 1 + l];

            float p1 = __shfl_up(a1, 1, 64);
            if (l == 0) p1 = NEG;

            float u0 = lae2(a0, p1) + lpb;
            float u1 = lae3(a1, a0, allow1 ? p1 : NEG) + lpl;
            float u2 = lae2(a2, a1) + lpb;

            bool act = (tbase + tt) < hl;
            a0 = act ? u0 : a0;
            a1 = act ? u1 : a1;
            a2 = act ? u2 : a2;
        }

        if (c < 7) {
            float* dst = ls[(c + 1) & 1];
            #pragma unroll
            for (int j = 0; j < 4; ++j) {
                int i = tid + j * 256;
                int tt = i >> 4, u4 = (i & 15) * 4;
                *(float4*)(&dst[tt * CS + u4]) = r4[j];
            }
            if (tid < 64) dst[tid * CS + 64] = r1;
        }
        __syncthreads();
    }

    if (tid < 64) {
        sh[2 * l] = a0;
        sh[2 * l + 1] = a1;
        if (l == 63) sh[128] = a2;
    }
    __syncthreads();

    if (tid == 0) {
        int L = ylens[b];
        ll_out[b] = lae2(sh[2 * L], sh[2 * L - 1]);
    }
}

__global__ void finalize(const float* __restrict__ ll, float* __restrict__ out) {
    if (threadIdx.x == 0 && blockIdx.x == 0) {
        float s = 0.0f;
        #pragma unroll
        for (int b = 0; b < Bn; ++b) s += ll[b];
        out[0] = -s / (float)Bn;
    }
}

extern "C" void kernel_launch(void* const* d_in, const int* in_sizes, int n_in,
                              void* d_out, int out_size, void* d_ws, size_t ws_size,
                              hipStream_t stream) {
    const float* hs    = (const float*)d_in[0];
    const int*   hlens = (const int*)d_in[1];
    const int*   ys    = (const int*)d_in[2];
    const int*   ylens = (const int*)d_in[3];
    const float* W     = (const float*)d_in[4];
    const float* bias  = (const float*)d_in[5];
    float* out = (float*)d_out;

    char* ws = (char*)d_ws;
    unsigned short* hs_b = (unsigned short*)(ws);                       // 4,194,304 B
    unsigned short* w_b  = (unsigned short*)(ws + 4194304);             // 2,228,224 B
    unsigned short* wg_b = (unsigned short*)(ws + 6422528);             //   655,360 B
    float* glp   = (float*)(ws + 7077888);                              // 2,621,440 B
    float* sep   = (float*)(ws + 9699328);                              // 1,114,112 B
    float* gbias = (float*)(ws + 10813440);                             //     5,120 B
    float* ll    = (float*)(ws + 10818560);                             //        64 B

    conv<<<1024, 256, 0, stream>>>(hs, W, bias, ys, hs_b, w_b, wg_b, gbias);
    gemm_se<<<dim3(64, NCB), 256, 0, stream>>>(hs_b, w_b, bias, sep);
    gemm_gather<<<dim3(4, 16), 256, 0, stream>>>(hs_b, wg_b, gbias, sep, glp);
    ctc_fwd<<<Bn, 256, 0, stream>>>(glp, ys, hlens, ylens, ll);
    finalize<<<1, 64, 0, stream>>>(ll, out);
}